// Round 1
// baseline (58.260 us; speedup 1.0000x reference)
//
#include <hip/hip_runtime.h>

// Shapes (fixed by the problem)
constexpr int TOK      = 1024 * 2048;   // B*S tokens
constexpr int NTHREADS = 1024 * 256;    // grid 1024 blocks x 256 threads
constexpr int ITERS    = TOK / NTHREADS; // 8 tokens per thread

// ws float layout:
// [0,32)     Gf[k=4][j=8]   = embed_w^T @ gate_w
// [32,40)    gb[8]          = embed_b @ gate_w
// [40,1064)  Wf[e=8][k=4][f=32] = embed_w^T @ wi[e]
// [1064,1320) ub[e=8][f=32] = embed_b @ wi[e]
// [1320,2344) Pf[e=8][f=32][o=4] = wo[e] @ proj_w^T
// [2344,2348) pb[4]
constexpr int WS_FLOATS = 2348;

__global__ void setup_fused(
    const float* __restrict__ ew,  // [16][4]
    const float* __restrict__ eb,  // [16]
    const float* __restrict__ gw,  // [16][8]
    const float* __restrict__ wi,  // [8][16][32]
    const float* __restrict__ wo,  // [8][32][16]
    const float* __restrict__ pw,  // [4][16]
    const float* __restrict__ pb,  // [4]
    float* __restrict__ ws)
{
    int idx = blockIdx.x * blockDim.x + threadIdx.x;
    if (idx >= WS_FLOATS) return;
    float v = 0.0f;
    if (idx < 32) {
        int k = idx >> 3, j = idx & 7;
        for (int i = 0; i < 16; ++i) v += ew[i * 4 + k] * gw[i * 8 + j];
    } else if (idx < 40) {
        int j = idx - 32;
        for (int i = 0; i < 16; ++i) v += eb[i] * gw[i * 8 + j];
    } else if (idx < 1064) {
        int r = idx - 40; int e = r >> 7, k = (r >> 5) & 3, f = r & 31;
        for (int i = 0; i < 16; ++i) v += ew[i * 4 + k] * wi[(e * 16 + i) * 32 + f];
    } else if (idx < 1320) {
        int r = idx - 1064; int e = r >> 5, f = r & 31;
        for (int i = 0; i < 16; ++i) v += eb[i] * wi[(e * 16 + i) * 32 + f];
    } else if (idx < 2344) {
        int r = idx - 1320; int e = r >> 7, f = (r >> 2) & 31, o = r & 3;
        for (int i = 0; i < 16; ++i) v += wo[(e * 32 + f) * 16 + i] * pw[o * 16 + i];
    } else {
        v = pb[idx - 2344];
    }
    ws[idx] = v;
}

// Expert strides padded so stride % 32 == 4 words: 8 experts land in
// disjoint 4-bank windows -> conflict-free ds_read_b128 for mixed experts.
constexpr int WF_STRIDE = 132;  // 4*32 = 128 -> 132
constexpr int UB_STRIDE = 36;   // 32 -> 36
constexpr int PF_STRIDE = 132;  // 32*4 = 128 -> 132

__global__ __launch_bounds__(256) void moe_main(
    const float* __restrict__ x,   // [T][4]
    const float* __restrict__ ws,  // fused weights
    float* __restrict__ out)       // [T][4]
{
    __shared__ __align__(16) float sG[48];             // Gf[32], gb[8], pb[4]
    __shared__ __align__(16) float sWf[8 * WF_STRIDE];
    __shared__ __align__(16) float sUb[8 * UB_STRIDE];
    __shared__ __align__(16) float sPf[8 * PF_STRIDE];

    const int tid = threadIdx.x;

    if (tid < 44) sG[tid] = ws[tid < 40 ? tid : (2344 + tid - 40)];
    {
        int i = tid;
        #pragma unroll
        for (int rep = 0; rep < 4; ++rep, i += 256) {   // 1024 elems each
            int e = i >> 7, r = i & 127;
            sWf[e * WF_STRIDE + r] = ws[40 + i];
            sPf[e * PF_STRIDE + r] = ws[1320 + i];
        }
    }
    if (tid < 256) {
        int e = tid >> 5, r = tid & 31;
        sUb[e * UB_STRIDE + r] = ws[1064 + tid];
    }
    __syncthreads();

    const float4* __restrict__ x4 = (const float4*)x;
    float4* __restrict__ o4       = (float4*)out;

    // Hoist wave-uniform gate/proj weights to registers (reused for 8 tokens).
    float4 w_gb0 = *(const float4*)&sG[32];
    float4 w_gb1 = *(const float4*)&sG[36];
    float4 w_pb  = *(const float4*)&sG[40];
    float4 Gr[8];
    #pragma unroll
    for (int q = 0; q < 8; ++q) Gr[q] = ((const float4*)sG)[q];
    // Gr[2k+0] = Gf[k][0..3], Gr[2k+1] = Gf[k][4..7]

    constexpr float LOG2E   = 1.4426950408889634f;
    constexpr float GELU_K  = 2.3025850929940457f;  // 2*0.7978845608*log2(e)
    constexpr float GELU_B  = 0.044715f;

    int t = blockIdx.x * blockDim.x + tid;
    for (int it = 0; it < ITERS; ++it, t += NTHREADS) {
        float4 xv = x4[t];
        float xk[4] = {xv.x, xv.y, xv.z, xv.w};

        // --- gate logits: g = x @ Gf + gb ---
        float4 ga = w_gb0, gbv = w_gb1;
        #pragma unroll
        for (int k = 0; k < 4; ++k) {
            ga.x  = fmaf(xk[k], Gr[2 * k].x,     ga.x);
            ga.y  = fmaf(xk[k], Gr[2 * k].y,     ga.y);
            ga.z  = fmaf(xk[k], Gr[2 * k].z,     ga.z);
            ga.w  = fmaf(xk[k], Gr[2 * k].w,     ga.w);
            gbv.x = fmaf(xk[k], Gr[2 * k + 1].x, gbv.x);
            gbv.y = fmaf(xk[k], Gr[2 * k + 1].y, gbv.y);
            gbv.z = fmaf(xk[k], Gr[2 * k + 1].z, gbv.z);
            gbv.w = fmaf(xk[k], Gr[2 * k + 1].w, gbv.w);
        }
        float g[8] = {ga.x, ga.y, ga.z, ga.w, gbv.x, gbv.y, gbv.z, gbv.w};

        // --- top-1: argmax (first max, matches jnp.argmax) + softmax max-prob ---
        float gmax = g[0]; int e = 0;
        #pragma unroll
        for (int j = 1; j < 8; ++j) {
            if (g[j] > gmax) { gmax = g[j]; e = j; }
        }
        float ssum = 0.0f;
        #pragma unroll
        for (int j = 0; j < 8; ++j) ssum += exp2f((g[j] - gmax) * LOG2E);
        float top_p = __builtin_amdgcn_rcpf(ssum);  // exp(0)/sum = 1/sum

        // --- expert FFN hidden: u = x @ Wf[e] + ub[e] ---
        const float4* wfe = (const float4*)(sWf + e * WF_STRIDE);
        const float4* ube = (const float4*)(sUb + e * UB_STRIDE);
        const float4* pfe = (const float4*)(sPf + e * PF_STRIDE);

        float u[32];
        #pragma unroll
        for (int q = 0; q < 8; ++q) {
            float4 b = ube[q];
            u[4 * q + 0] = b.x; u[4 * q + 1] = b.y;
            u[4 * q + 2] = b.z; u[4 * q + 3] = b.w;
        }
        #pragma unroll
        for (int k = 0; k < 4; ++k) {
            #pragma unroll
            for (int q = 0; q < 8; ++q) {
                float4 w = wfe[k * 8 + q];
                u[4 * q + 0] = fmaf(xk[k], w.x, u[4 * q + 0]);
                u[4 * q + 1] = fmaf(xk[k], w.y, u[4 * q + 1]);
                u[4 * q + 2] = fmaf(xk[k], w.z, u[4 * q + 2]);
                u[4 * q + 3] = fmaf(xk[k], w.w, u[4 * q + 3]);
            }
        }

        // --- gelu (tanh approx, NaN-safe): v * t/(1+t), t = 2^(K*v*(1+b*v^2)) ---
        #pragma unroll
        for (int f = 0; f < 32; ++f) {
            float v   = u[f];
            float m   = fmaf(GELU_B * v, v, 1.0f);      // 1 + b*v^2
            float arg = (GELU_K * v) * m;
            float tt  = exp2f(arg);
            float r   = __builtin_amdgcn_rcpf(tt + 1.0f);
            u[f] = fmaf(-v, r, v);                      // v*(1 - 1/(1+t))
        }

        // --- fused wo+proj: acc = a @ Pf[e]; out = top_p*acc + pb ---
        float4 acc = {0.0f, 0.0f, 0.0f, 0.0f};
        #pragma unroll
        for (int f = 0; f < 32; ++f) {
            float4 w = pfe[f];
            acc.x = fmaf(u[f], w.x, acc.x);
            acc.y = fmaf(u[f], w.y, acc.y);
            acc.z = fmaf(u[f], w.z, acc.z);
            acc.w = fmaf(u[f], w.w, acc.w);
        }
        float4 ov;
        ov.x = fmaf(top_p, acc.x, w_pb.x);
        ov.y = fmaf(top_p, acc.y, w_pb.y);
        ov.z = fmaf(top_p, acc.z, w_pb.z);
        ov.w = fmaf(top_p, acc.w, w_pb.w);
        o4[t] = ov;
    }
}

extern "C" void kernel_launch(void* const* d_in, const int* in_sizes, int n_in,
                              void* d_out, int out_size, void* d_ws, size_t ws_size,
                              hipStream_t stream) {
    const float* x  = (const float*)d_in[0];
    const float* ew = (const float*)d_in[1];
    const float* eb = (const float*)d_in[2];
    const float* gw = (const float*)d_in[3];
    const float* wi = (const float*)d_in[4];
    const float* wo = (const float*)d_in[5];
    const float* pw = (const float*)d_in[6];
    const float* pb = (const float*)d_in[7];
    float* ws  = (float*)d_ws;
    float* out = (float*)d_out;

    setup_fused<<<(WS_FLOATS + 255) / 256, 256, 0, stream>>>(ew, eb, gw, wi, wo, pw, pb, ws);
    moe_main<<<NTHREADS / 256, 256, 0, stream>>>(x, ws, out);
}

// Round 2
// 45.829 us; speedup vs baseline: 1.2712x; 1.2712x over previous
//
#include <hip/hip_runtime.h>

// Shapes (fixed by the problem)
constexpr int TOK      = 1024 * 2048;     // B*S tokens
constexpr int NTHREADS = 2048 * 256;      // grid 2048 blocks x 256 threads
constexpr int ITERS    = TOK / NTHREADS;  // 4 tokens per thread

typedef float f32x4 __attribute__((ext_vector_type(4)));
typedef float f32x2 __attribute__((ext_vector_type(2)));

// ws float layout:
// [0,32)      Gf[k=4][j=8]       = embed_w^T @ gate_w
// [32,40)     gb[8]              = embed_b @ gate_w
// [40,1064)   Wf[e=8][k=4][f=32] = embed_w^T @ wi[e]
// [1064,1320) ub[e=8][f=32]      = embed_b @ wi[e]
// [1320,2344) Pf[e=8][f=32][o=4] = wo[e] @ proj_w^T
// [2344,2348) pb[4]
constexpr int WS_FLOATS = 2348;

__global__ void setup_fused(
    const float* __restrict__ ew,  // [16][4]
    const float* __restrict__ eb,  // [16]
    const float* __restrict__ gw,  // [16][8]
    const float* __restrict__ wi,  // [8][16][32]
    const float* __restrict__ wo,  // [8][32][16]
    const float* __restrict__ pw,  // [4][16]
    const float* __restrict__ pb,  // [4]
    float* __restrict__ ws)
{
    int idx = blockIdx.x * blockDim.x + threadIdx.x;
    if (idx >= WS_FLOATS) return;
    float v = 0.0f;
    if (idx < 32) {
        int k = idx >> 3, j = idx & 7;
        for (int i = 0; i < 16; ++i) v += ew[i * 4 + k] * gw[i * 8 + j];
    } else if (idx < 40) {
        int j = idx - 32;
        for (int i = 0; i < 16; ++i) v += eb[i] * gw[i * 8 + j];
    } else if (idx < 1064) {
        int r = idx - 40; int e = r >> 7, k = (r >> 5) & 3, f = r & 31;
        for (int i = 0; i < 16; ++i) v += ew[i * 4 + k] * wi[(e * 16 + i) * 32 + f];
    } else if (idx < 1320) {
        int r = idx - 1064; int e = r >> 5, f = r & 31;
        for (int i = 0; i < 16; ++i) v += eb[i] * wi[(e * 16 + i) * 32 + f];
    } else if (idx < 2344) {
        int r = idx - 1320; int e = r >> 7, f = (r >> 2) & 31, o = r & 3;
        for (int i = 0; i < 16; ++i) v += wo[(e * 32 + f) * 16 + i] * pw[o * 16 + i];
    } else {
        v = pb[idx - 2344];
    }
    ws[idx] = v;
}

// Expert strides padded so stride % 32 == 4 words: 8 experts land in
// disjoint 4-bank windows -> conflict-free mixed-expert ds_read_b128.
constexpr int WF_STRIDE = 132;  // 4*32 = 128 -> 132
constexpr int UB_STRIDE = 36;   // 32 -> 36
constexpr int PF_STRIDE = 132;  // 32*4 = 128 -> 132

__device__ __forceinline__ f32x4 splat4(float s) { return (f32x4){s, s, s, s}; }

__global__ __launch_bounds__(256) void moe_main(
    const float* __restrict__ x,   // [T][4]
    const float* __restrict__ ws,  // fused weights
    float* __restrict__ out)       // [T][4]
{
    __shared__ __align__(16) float sG[48];             // Gf[32], gb[8], pb[4]
    __shared__ __align__(16) float sWf[8 * WF_STRIDE];
    __shared__ __align__(16) float sUb[8 * UB_STRIDE];
    __shared__ __align__(16) float sPf[8 * PF_STRIDE];

    const int tid = threadIdx.x;

    if (tid < 44) sG[tid] = ws[tid < 40 ? tid : (2344 + tid - 40)];
    {
        int i = tid;
        #pragma unroll
        for (int rep = 0; rep < 4; ++rep, i += 256) {   // 1024 elems each
            int e = i >> 7, r = i & 127;
            sWf[e * WF_STRIDE + r] = ws[40 + i];
            sPf[e * PF_STRIDE + r] = ws[1320 + i];
        }
    }
    {
        int e = tid >> 5, r = tid & 31;
        sUb[e * UB_STRIDE + r] = ws[1064 + tid];
    }
    __syncthreads();

    const f32x4* __restrict__ x4 = (const f32x4*)x;
    f32x4* __restrict__ o4       = (f32x4*)out;

    // Wave-uniform gate/proj params hoisted to registers (reused all iters).
    f32x4 Gr[8];   // Gr[2k+0]=Gf[k][0..3], Gr[2k+1]=Gf[k][4..7]
    #pragma unroll
    for (int q = 0; q < 8; ++q) Gr[q] = ((const f32x4*)sG)[q];
    f32x4 w_gb0 = ((const f32x4*)sG)[8];
    f32x4 w_gb1 = ((const f32x4*)sG)[9];
    f32x4 w_pb  = ((const f32x4*)sG)[10];

    constexpr float LOG2E  = 1.4426950408889634f;
    constexpr float GELU_K = 2.3025850929940457f;   // 2*0.7978845608*log2(e)
    constexpr float GELU_B = 0.044715f;
    const f32x4 one4 = splat4(1.0f);

    int t = blockIdx.x * blockDim.x + tid;
    for (int it = 0; it < ITERS; ++it, t += NTHREADS) {
        f32x4 xv = x4[t];

        // --- gate logits: g = x @ Gf + gb (packed) ---
        f32x4 ga = w_gb0, gb2 = w_gb1;
        #pragma unroll
        for (int k = 0; k < 4; ++k) {
            f32x4 xs = splat4(xv[k]);
            ga  = __builtin_elementwise_fma(xs, Gr[2 * k],     ga);
            gb2 = __builtin_elementwise_fma(xs, Gr[2 * k + 1], gb2);
        }
        float g[8] = {ga[0], ga[1], ga[2], ga[3], gb2[0], gb2[1], gb2[2], gb2[3]};

        // --- top-1: first-argmax + softmax max prob ---
        float gmax = g[0]; int e = 0;
        #pragma unroll
        for (int j = 1; j < 8; ++j) {
            if (g[j] > gmax) { gmax = g[j]; e = j; }
        }
        float ssum = 0.0f;
        #pragma unroll
        for (int j = 0; j < 8; ++j)
            ssum += __builtin_amdgcn_exp2f((g[j] - gmax) * LOG2E);
        float top_p = __builtin_amdgcn_rcpf(ssum);

        // --- expert FFN hidden: U = x @ Wf[e] + ub[e] (packed) ---
        const f32x4* wfe = (const f32x4*)(sWf + e * WF_STRIDE);
        const f32x4* ube = (const f32x4*)(sUb + e * UB_STRIDE);
        const f32x4* pfe = (const f32x4*)(sPf + e * PF_STRIDE);

        f32x4 U[8];
        #pragma unroll
        for (int q = 0; q < 8; ++q) U[q] = ube[q];
        #pragma unroll
        for (int k = 0; k < 4; ++k) {
            f32x4 xs = splat4(xv[k]);
            #pragma unroll
            for (int q = 0; q < 8; ++q)
                U[q] = __builtin_elementwise_fma(xs, wfe[k * 8 + q], U[q]);
        }

        // --- gelu (tanh form, NaN-safe): v - v/(1+t), t = 2^(K'*v*(1+b*v^2)) ---
        #pragma unroll
        for (int q = 0; q < 8; ++q) {
            f32x4 v  = U[q];
            f32x4 m  = __builtin_elementwise_fma(v * splat4(GELU_B), v, one4);
            f32x4 a  = (v * splat4(GELU_K)) * m;
            f32x4 tt;
            #pragma unroll
            for (int c = 0; c < 4; ++c) tt[c] = __builtin_amdgcn_exp2f(a[c]);
            tt = tt + one4;
            f32x4 r;
            #pragma unroll
            for (int c = 0; c < 4; ++c) r[c] = __builtin_amdgcn_rcpf(tt[c]);
            U[q] = __builtin_elementwise_fma(-v, r, v);
        }

        // --- fused wo+proj: acc = gelu(U) @ Pf[e]; out = top_p*acc + pb ---
        f32x4 acc = splat4(0.0f);
        #pragma unroll
        for (int q = 0; q < 8; ++q) {
            #pragma unroll
            for (int c = 0; c < 4; ++c)
                acc = __builtin_elementwise_fma(splat4(U[q][c]), pfe[q * 4 + c], acc);
        }
        o4[t] = __builtin_elementwise_fma(splat4(top_p), acc, w_pb);
    }
}

extern "C" void kernel_launch(void* const* d_in, const int* in_sizes, int n_in,
                              void* d_out, int out_size, void* d_ws, size_t ws_size,
                              hipStream_t stream) {
    const float* x  = (const float*)d_in[0];
    const float* ew = (const float*)d_in[1];
    const float* eb = (const float*)d_in[2];
    const float* gw = (const float*)d_in[3];
    const float* wi = (const float*)d_in[4];
    const float* wo = (const float*)d_in[5];
    const float* pw = (const float*)d_in[6];
    const float* pb = (const float*)d_in[7];
    float* ws  = (float*)d_ws;
    float* out = (float*)d_out;

    setup_fused<<<(WS_FLOATS + 255) / 256, 256, 0, stream>>>(ew, eb, gw, wi, wo, pw, pb, ws);
    moe_main<<<NTHREADS / 256, 256, 0, stream>>>(x, ws, out);
}